// Round 1
// 123.743 us; speedup vs baseline: 1.0591x; 1.0591x over previous
//
#include <hip/hip_runtime.h>

#define SIGMA 0.5f
#define BB 32
#define NVV 6890
#define NFF 13776
#define MAXC 8
#define NCC (NFF * MAXC)                 // 110208 pairs per batch

// fused kernel geometry: one block per (batch, slot); 8 slots per batch.
#define SLOTS 8
#define PAIRS_PER_SLOT (NCC / SLOTS)     // 13776 exactly
#define THREADS 1024
#define NBLOCK (BB * SLOTS)              // 256 blocks == 256 CUs, 1 block/CU (LDS-bound)

typedef int v4i __attribute__((ext_vector_type(4)));

__device__ __forceinline__ float3 loadv3(const float* __restrict__ p) {
    return make_float3(p[0], p[1], p[2]);
}

// one-sided conic penetration: query tri q0..q2 in field of tri a0..a2
__device__ __forceinline__ float conePen(float3 a0, float3 a1, float3 a2,
                                         float3 q0, float3 q1, float3 q2) {
    const float third = 1.0f / 3.0f;
    float cx = (a0.x + a1.x + a2.x) * third;
    float cy = (a0.y + a1.y + a2.y) * third;
    float cz = (a0.z + a1.z + a2.z) * third;
    float e1x = a1.x - a0.x, e1y = a1.y - a0.y, e1z = a1.z - a0.z;
    float e2x = a2.x - a0.x, e2y = a2.y - a0.y, e2z = a2.z - a0.z;
    float nx = e1y * e2z - e1z * e2y;
    float ny = e1z * e2x - e1x * e2z;
    float nz = e1x * e2y - e1y * e2x;
    float inv = 1.0f / (sqrtf(nx * nx + ny * ny + nz * nz) + 1e-8f);
    nx *= inv; ny *= inv; nz *= inv;
    float3 q[3] = {q0, q1, q2};
    float pen = 0.0f;
#pragma unroll
    for (int v = 0; v < 3; ++v) {
        float dx = q[v].x - cx, dy = q[v].y - cy, dz = q[v].z - cz;
        float h = dx * nx + dy * ny + dz * nz;
        float r = sqrtf(dx * dx + dy * dy + dz * dz);
        float phi = fmaxf(SIGMA - r, 0.0f);
        pen += (h < 0.0f) ? phi * h * h : 0.0f;
    }
    return pen;
}

__device__ __forceinline__ float3 ldsVert(const float* __restrict__ sv, int v) {
    return make_float3(sv[3 * v + 0], sv[3 * v + 1], sv[3 * v + 2]);
}

// symmetric penetration for one collision pair, all gathers from LDS
__device__ __forceinline__ float pairPen(const float* __restrict__ sv,
                                         const unsigned int* __restrict__ fw,
                                         const unsigned char* __restrict__ fb,
                                         int r, int it) {
    if (r < 0) return 0.0f;               // padding slot
    const int g = it < 0 ? 0 : it;        // reference clamps with max(idx,0)
    unsigned int wa = fw[r];
    unsigned int wb = fw[g];
    int a0 = wa & 8191, a1 = (wa >> 13) & 8191, a2 = (int)(wa >> 26) | ((int)fb[r] << 6);
    int b0 = wb & 8191, b1 = (wb >> 13) & 8191, b2 = (int)(wb >> 26) | ((int)fb[g] << 6);
    float3 A0 = ldsVert(sv, a0), A1 = ldsVert(sv, a1), A2 = ldsVert(sv, a2);
    float3 B0 = ldsVert(sv, b0), B1 = ldsVert(sv, b1), B2 = ldsVert(sv, b2);
    return conePen(A0, A1, A2, B0, B1, B2) + conePen(B0, B1, B2, A0, A1, A2);
}

// ---------------- fused: stage batch verts+faces in LDS, eval pairs --------
__global__ __launch_bounds__(THREADS) void fused_kernel(
    const float* __restrict__ vertices,   // [B, NV, 3]
    const int*   __restrict__ faces,      // [NF, 3]
    const int*   __restrict__ cidx,       // [B, NC, 2]
    float*       __restrict__ partials)   // [NBLOCK]
{
    // 82,680 + 55,104 + 13,776 + 64 = 151,624 B  <= 160 KiB
    __shared__ float         s_v[NVV * 3];    // fp32 verts of this batch
    __shared__ unsigned int  s_fw[NFF];       // idx0 | idx1<<13 | (idx2&63)<<26
    __shared__ unsigned char s_fb[NFF];       // idx2 >> 6
    __shared__ float         s_red[16];

    const int b   = blockIdx.x;               // x-major dispatch -> XCD b%8
    const int sl  = blockIdx.y;
    const int tid = threadIdx.x;

    // ---- stage vertices (coalesced fp32 copy) ----
    const float* vb = vertices + (size_t)b * (NVV * 3);
    for (int i = tid; i < NVV * 3; i += THREADS)
        s_v[i] = vb[i];

    // ---- stage faces, bit-packed to 5 B (all idx < 6890 < 2^13) ----
    for (int f = tid; f < NFF; f += THREADS) {
        int i0 = faces[3 * f + 0];
        int i1 = faces[3 * f + 1];
        int i2 = faces[3 * f + 2];
        s_fw[f] = (unsigned int)i0 | ((unsigned int)i1 << 13)
                | ((unsigned int)(i2 & 63) << 26);
        s_fb[f] = (unsigned char)(i2 >> 6);
    }
    __syncthreads();

    // ---- pair loop: 2 pairs per int4 load, only coalesced global traffic ----
    float pen = 0.0f;
    const v4i* c4 = (const v4i*)(cidx + ((size_t)b * NCC + (size_t)sl * PAIRS_PER_SLOT) * 2);
    for (int q = tid; 2 * q < PAIRS_PER_SLOT; q += THREADS) {
        v4i pr = __builtin_nontemporal_load(c4 + q);   // {recv0, intr0, recv1, intr1}
        pen += pairPen(s_v, s_fw, s_fb, pr.x, pr.y);
        pen += pairPen(s_v, s_fw, s_fb, pr.z, pr.w);
    }

    // ---- block reduction: 16 waves ----
#pragma unroll
    for (int off = 32; off > 0; off >>= 1)
        pen += __shfl_down(pen, off, 64);
    const int lane = tid & 63;
    const int wv   = tid >> 6;
    if (lane == 0) s_red[wv] = pen;
    __syncthreads();
    if (tid == 0) {
        float t = 0.0f;
#pragma unroll
        for (int w = 0; w < 16; ++w) t += s_red[w];
        partials[b * SLOTS + sl] = t;
    }
}

// ---------------- fold 256 partials, apply weight / B ----------------
__global__ __launch_bounds__(256) void fin2_kernel(
    const float* __restrict__ partials,
    const float* __restrict__ weight,
    float*       __restrict__ out)
{
    float s = partials[threadIdx.x];      // NBLOCK == 256
#pragma unroll
    for (int off = 32; off > 0; off >>= 1)
        s += __shfl_down(s, off, 64);
    __shared__ float smem[4];
    const int lane = threadIdx.x & 63;
    const int wv   = threadIdx.x >> 6;
    if (lane == 0) smem[wv] = s;
    __syncthreads();
    if (threadIdx.x == 0)
        out[0] = (smem[0] + smem[1] + smem[2] + smem[3]) * weight[0] * (1.0f / (float)BB);
}

// ---------------- fallback: direct per-pair with atomics (tiny ws) --------
__global__ void init_kernel(float* __restrict__ accum) { accum[0] = 0.0f; }

__global__ __launch_bounds__(256) void pen_direct(
    const float* __restrict__ vertices, const int* __restrict__ faces,
    const int2* __restrict__ cidx, float* __restrict__ accum)
{
    const int i = blockIdx.x * blockDim.x + threadIdx.x;
    float pen = 0.0f;
    if (i < BB * NCC) {
        const int b = i / NCC;
        const int2 pr = cidx[i];
        if (pr.x >= 0) {
            const int f0 = pr.x;
            const int f1 = pr.y < 0 ? 0 : pr.y;
            const float* vb = vertices + (size_t)b * (NVV * 3);
            float3 a0 = loadv3(vb + (size_t)faces[f0*3+0] * 3);
            float3 a1 = loadv3(vb + (size_t)faces[f0*3+1] * 3);
            float3 a2 = loadv3(vb + (size_t)faces[f0*3+2] * 3);
            float3 b0 = loadv3(vb + (size_t)faces[f1*3+0] * 3);
            float3 b1 = loadv3(vb + (size_t)faces[f1*3+1] * 3);
            float3 b2 = loadv3(vb + (size_t)faces[f1*3+2] * 3);
            pen = conePen(a0,a1,a2,b0,b1,b2) + conePen(b0,b1,b2,a0,a1,a2);
        }
    }
#pragma unroll
    for (int off = 32; off > 0; off >>= 1)
        pen += __shfl_down(pen, off, 64);
    __shared__ float smem[4];
    const int lane = threadIdx.x & 63;
    const int wv   = threadIdx.x >> 6;
    if (lane == 0) smem[wv] = pen;
    __syncthreads();
    if (threadIdx.x == 0)
        atomicAdd(accum, smem[0] + smem[1] + smem[2] + smem[3]);
}

__global__ void fin_kernel(const float* __restrict__ accum,
                           const float* __restrict__ weight,
                           float* __restrict__ out)
{
    out[0] = accum[0] * weight[0] * (1.0f / (float)BB);
}

extern "C" void kernel_launch(void* const* d_in, const int* in_sizes, int n_in,
                              void* d_out, int out_size, void* d_ws, size_t ws_size,
                              hipStream_t stream) {
    const float* vertices = (const float*)d_in[4];
    const float* weight   = (const float*)d_in[5];
    const int*   faces    = (const int*)d_in[6];
    const int*   cidx     = (const int*)d_in[7];
    float* out = (float*)d_out;

    if (ws_size >= NBLOCK * sizeof(float)) {
        float* partials = (float*)d_ws;
        fused_kernel<<<dim3(BB, SLOTS), dim3(THREADS), 0, stream>>>(
            vertices, faces, cidx, partials);
        fin2_kernel<<<dim3(1), dim3(256), 0, stream>>>(partials, weight, out);
    } else {
        float* accum = (float*)d_ws;
        const int totalPairs = BB * NCC;
        init_kernel<<<dim3(1), dim3(1), 0, stream>>>(accum);
        pen_direct<<<dim3((totalPairs + 255) / 256), dim3(256), 0, stream>>>(
            vertices, faces, (const int2*)cidx, accum);
        fin_kernel<<<dim3(1), dim3(1), 0, stream>>>(accum, weight, out);
    }
}